// Round 6
// baseline (277.003 us; speedup 1.0000x reference)
//
#include <hip/hip_runtime.h>
#include <cstddef>

#define B_ 8
#define H_ 1024
#define W_ 1024
#define NW_ 5
#define CH_ 2                 // rows per chunk (= rows per wave in K1)
#define NCH_ (H_ / CH_)       // 512 chunk rows per batch
#define SEG_ 16               // chunk rows per scan segment
#define NSEG_ (NCH_ / SEG_)   // 32 segments

// ---------------------------------------------------------------------------
// K1: fused row-prefix + intra-chunk column prefix + chunk sums.
// ROUND-6 CHANGES (K1 was the never-tested constant across R1-R5):
//  (a) ALL input float4 loads hoisted to the top — issued back-to-back
//      before any shfl chain, so HBM latency overlaps the serial
//      6-round ds_bpermute scans instead of serializing with them.
//  (b) CH 4->2: halve rows/wave -> 1024 blocks, 4/CU, 16 waves/CU
//      (was 8) to hide the cross-lane-chain latency.
// Math per element unchanged; centered values keep absmax ~4e-3.
// ---------------------------------------------------------------------------
__global__ __launch_bounds__(256) void k_rowpart(const float* __restrict__ x,
                                                 float* __restrict__ P1,
                                                 float* __restrict__ P2,
                                                 float* __restrict__ part1,
                                                 float* __restrict__ part2) {
  const int b = blockIdx.y;
  const int wave = threadIdx.x >> 6, lane = threadIdx.x & 63;
  const int y0 = blockIdx.x * (4 * CH_) + wave * CH_;   // 4 waves x CH_ rows

  // --- prefetch: all 8 float4 loads in flight before any compute ---
  float4 v[CH_][4];
  #pragma unroll
  for (int rr = 0; rr < CH_; ++rr) {
    const size_t rowoff = ((size_t)b * H_ + (y0 + rr)) * W_;
    #pragma unroll
    for (int c = 0; c < 4; ++c)
      v[rr][c] = reinterpret_cast<const float4*>(x + rowoff + c * 256)[lane];
  }

  float4 acc1[4], acc2[4];
  #pragma unroll
  for (int c = 0; c < 4; ++c) {
    acc1[c] = make_float4(0.f, 0.f, 0.f, 0.f);
    acc2[c] = make_float4(0.f, 0.f, 0.f, 0.f);
  }

  #pragma unroll
  for (int rr = 0; rr < CH_; ++rr) {
    const size_t rowoff = ((size_t)b * H_ + (y0 + rr)) * W_;
    float carry1 = 0.f, carry2 = 0.f;
    #pragma unroll
    for (int c = 0; c < 4; ++c) {
      const float4 vv = v[rr][c];
      float l1[4], l2[4];
      l1[0] = vv.x - 0.5f;
      l1[1] = l1[0] + (vv.y - 0.5f);
      l1[2] = l1[1] + (vv.z - 0.5f);
      l1[3] = l1[2] + (vv.w - 0.5f);
      l2[0] = vv.x * vv.x - (1.0f / 3.0f);
      l2[1] = l2[0] + (vv.y * vv.y - (1.0f / 3.0f));
      l2[2] = l2[1] + (vv.z * vv.z - (1.0f / 3.0f));
      l2[3] = l2[2] + (vv.w * vv.w - (1.0f / 3.0f));
      const float s1 = l1[3], s2 = l2[3];
      float inc1 = s1, inc2 = s2;
      #pragma unroll
      for (int off = 1; off < 64; off <<= 1) {
        const float t1 = __shfl_up(inc1, off);
        const float t2 = __shfl_up(inc2, off);
        if (lane >= off) { inc1 += t1; inc2 += t2; }
      }
      const float base1 = carry1 + inc1 - s1;
      const float base2 = carry2 + inc2 - s2;
      acc1[c].x += base1 + l1[0]; acc1[c].y += base1 + l1[1];
      acc1[c].z += base1 + l1[2]; acc1[c].w += base1 + l1[3];
      acc2[c].x += base2 + l2[0]; acc2[c].y += base2 + l2[1];
      acc2[c].z += base2 + l2[2]; acc2[c].w += base2 + l2[3];
      reinterpret_cast<float4*>(P1 + rowoff + c * 256)[lane] = acc1[c];
      reinterpret_cast<float4*>(P2 + rowoff + c * 256)[lane] = acc2[c];
      carry1 += __shfl(inc1, 63);
      carry2 += __shfl(inc2, 63);
    }
  }

  // wave's chunk sum -> part[b][cc][:]
  const int cc = y0 / CH_;
  const size_t po = ((size_t)(b * NCH_ + cc)) * W_;
  #pragma unroll
  for (int c = 0; c < 4; ++c) {
    reinterpret_cast<float4*>(part1 + po + c * 256)[lane] = acc1[c];
    reinterpret_cast<float4*>(part2 + po + c * 256)[lane] = acc2[c];
  }
}

// ---------------------------------------------------------------------------
// K2a: segmented exclusive scan of the chunk-sum rows. Block (256-col
// strip, 16-chunk-row segment, b): scans its 16 rows in place, writes the
// segment total to super[b][seg][x]. Now 1024 blocks (NSEG_=32).
// ---------------------------------------------------------------------------
__global__ __launch_bounds__(256) void k_segscan(float* __restrict__ part1,
                                                 float* __restrict__ part2,
                                                 float* __restrict__ super1,
                                                 float* __restrict__ super2) {
  const int xx = blockIdx.x * 256 + threadIdx.x;
  const int seg = blockIdx.y, b = blockIdx.z;
  const int cc0 = seg * SEG_;
  float r1 = 0.f, r2 = 0.f;
  #pragma unroll
  for (int i = 0; i < SEG_; ++i) {
    const size_t o = ((size_t)(b * NCH_ + cc0 + i)) * W_ + xx;
    const float t1 = part1[o], t2 = part2[o];
    part1[o] = r1; part2[o] = r2;
    r1 += t1; r2 += t2;
  }
  const size_t so = ((size_t)(b * NSEG_ + seg)) * W_ + xx;
  super1[so] = r1;
  super2[so] = r2;
}

// ---------------------------------------------------------------------------
// K2c: materialize the FULL SAT in place. Block (cc, b):
// pp[cc] = sum super[0..seg-1] (L2-hot, <=31 rows) + part_exclusive[cc],
// then add pp into the chunk's CH_=2 P-rows. 4096 blocks.
// ---------------------------------------------------------------------------
__global__ __launch_bounds__(256) void k_addpp(float* __restrict__ P1,
                                               float* __restrict__ P2,
                                               const float* __restrict__ part1,
                                               const float* __restrict__ part2,
                                               const float* __restrict__ super1,
                                               const float* __restrict__ super2) {
  const int cc = blockIdx.x, b = blockIdx.y;
  const int seg = cc >> 4;        // SEG_=16
  const int t = threadIdx.x;      // thread t owns cols 4t..4t+3

  const size_t po = ((size_t)(b * NCH_ + cc)) * W_;
  float4 o1 = reinterpret_cast<const float4*>(part1 + po)[t];
  float4 o2 = reinterpret_cast<const float4*>(part2 + po)[t];
  for (int s = 0; s < seg; ++s) {   // block-uniform trip count, L2-hot rows
    const size_t so = ((size_t)(b * NSEG_ + s)) * W_;
    const float4 u1 = reinterpret_cast<const float4*>(super1 + so)[t];
    const float4 u2 = reinterpret_cast<const float4*>(super2 + so)[t];
    o1.x += u1.x; o1.y += u1.y; o1.z += u1.z; o1.w += u1.w;
    o2.x += u2.x; o2.y += u2.y; o2.z += u2.z; o2.w += u2.w;
  }

  float* p1 = P1 + ((size_t)b * H_ + (size_t)cc * CH_) * W_;
  float* p2 = P2 + ((size_t)b * H_ + (size_t)cc * CH_) * W_;
  #pragma unroll
  for (int i = 0; i < CH_; ++i) {
    float4 v1 = reinterpret_cast<const float4*>(p1 + (size_t)i * W_)[t];
    float4 v2 = reinterpret_cast<const float4*>(p2 + (size_t)i * W_)[t];
    v1.x += o1.x; v1.y += o1.y; v1.z += o1.z; v1.w += o1.w;
    v2.x += o2.x; v2.y += o2.y; v2.z += o2.z; v2.w += o2.w;
    reinterpret_cast<float4*>(p1 + (size_t)i * W_)[t] = v1;
    reinterpret_cast<float4*>(p2 + (size_t)i * W_)[t] = v2;
  }
}

// ---------------------------------------------------------------------------
// K3: unchanged from R5 (lean 20-load form, b-pinned mapping). Reads the
// complete SAT; per-row vertical-difference strips in LDS.
// ---------------------------------------------------------------------------
__global__ __launch_bounds__(256) void k_out(const float* __restrict__ S1,
                                             const float* __restrict__ S2,
                                             const float* __restrict__ kk,
                                             const float* __restrict__ RR,
                                             float* __restrict__ out) {
  const int i = blockIdx.x;
  const int b = i & 7;        // batch pinned to XCD
  const int y = i >> 3;       // ascending y within each XCD
  const int t = threadIdx.x;

  __shared__ float lds[2 * NW_ * W_];  // 40 KB

  const float* base1 = S1 + (size_t)b * H_ * W_;
  const float* base2 = S2 + (size_t)b * H_ * W_;
  const int rad[NW_] = {3, 7, 15, 31, 63};

  #pragma unroll
  for (int w = 0; w < NW_; ++w) {
    const int r = rad[w];
    const int yB = min(y + r, H_ - 1);
    const float4 fb1 = reinterpret_cast<const float4*>(base1 + (size_t)yB * W_)[t];
    const float4 fb2 = reinterpret_cast<const float4*>(base2 + (size_t)yB * W_)[t];
    float4 ft1 = {0.f, 0.f, 0.f, 0.f}, ft2 = {0.f, 0.f, 0.f, 0.f};
    const int yT = y - r - 1;
    if (yT >= 0) {   // block-uniform branch
      ft1 = reinterpret_cast<const float4*>(base1 + (size_t)yT * W_)[t];
      ft2 = reinterpret_cast<const float4*>(base2 + (size_t)yT * W_)[t];
    }
    float4 d1, d2;
    d1.x = fb1.x - ft1.x; d1.y = fb1.y - ft1.y; d1.z = fb1.z - ft1.z; d1.w = fb1.w - ft1.w;
    d2.x = fb2.x - ft2.x; d2.y = fb2.y - ft2.y; d2.z = fb2.z - ft2.z; d2.w = fb2.w - ft2.w;
    reinterpret_cast<float4*>(lds + (size_t)(2 * w) * W_)[t] = d1;
    reinterpret_cast<float4*>(lds + (size_t)(2 * w + 1) * W_)[t] = d2;
  }
  __syncthreads();

  #pragma unroll
  for (int w = 0; w < NW_; ++w) {
    const int r = rad[w];
    const float kw = kk[w];
    const float invR = __builtin_amdgcn_rcpf(RR[w]);
    const int yB = min(y + r, H_ - 1);
    const float rows = (float)(yB - max(y - r, 0) + 1);
    const float* D1 = lds + (size_t)(2 * w) * W_;
    const float* D2 = lds + (size_t)(2 * w + 1) * W_;
    float* orow = out + (((size_t)(b * NW_ + w)) * H_ + y) * W_;
    #pragma unroll
    for (int kp = 0; kp < 4; ++kp) {
      const int xx = t + kp * 256;
      const int xR = min(xx + r, W_ - 1);
      const int xL = xx - r - 1;
      float s1 = D1[xR];
      float s2 = D2[xR];
      if (xL >= 0) { s1 -= D1[xL]; s2 -= D2[xL]; }
      const float cols = (float)(xR - max(xx - r, 0) + 1);
      const float inv = __builtin_amdgcn_rcpf(rows * cols);
      const float Ex  = s1 * inv + 0.5f;
      const float Ex2 = s2 * inv + (1.0f / 3.0f);
      const float var = Ex2 - Ex * Ex;
      const float dev = __builtin_amdgcn_sqrtf(fmaxf(var, 1e-6f));
      orow[xx] = Ex * (1.0f + kw * (dev * invR - 1.0f));
    }
  }
}

// ---------------------------------------------------------------------------
extern "C" void kernel_launch(void* const* d_in, const int* in_sizes, int n_in,
                              void* d_out, int out_size, void* d_ws, size_t ws_size,
                              hipStream_t stream) {
  const float* x  = (const float*)d_in[0];
  const float* kk = (const float*)d_in[1];
  const float* RR = (const float*)d_in[2];
  float* out = (float*)d_out;

  const size_t plane = (size_t)B_ * H_ * W_;            // 32 MB per moment
  float* P1 = (float*)d_ws;
  float* P2 = P1 + plane;
  float* part1 = P2 + plane;                            // 16 MB each
  float* part2 = part1 + (size_t)B_ * NCH_ * W_;
  float* super1 = part2 + (size_t)B_ * NCH_ * W_;       // 1 MB each
  float* super2 = super1 + (size_t)B_ * NSEG_ * W_;     // total ws ~ 98 MB

  k_rowpart <<<dim3(H_ / (4 * CH_), B_),   256, 0, stream>>>(x, P1, P2, part1, part2);
  k_segscan <<<dim3(W_/256, NSEG_, B_),    256, 0, stream>>>(part1, part2, super1, super2);
  k_addpp   <<<dim3(NCH_, B_),             256, 0, stream>>>(P1, P2, part1, part2, super1, super2);
  k_out     <<<dim3(B_ * H_),              256, 0, stream>>>(P1, P2, kk, RR, out);
}

// Round 7
// 244.248 us; speedup vs baseline: 1.1341x; 1.1341x over previous
//
#include <hip/hip_runtime.h>
#include <cstddef>

#define B_ 8
#define H_ 1024
#define W_ 1024
#define NW_ 5
#define CHUNKS_ 32
#define CHROWS_ (H_ / CHUNKS_)   // 32

// ---------------------------------------------------------------------------
// ROUND-7: full revert to the round-0 best-known pipeline (249.0 us, the
// best measurement across 7 rounds; every structural variant since was
// neutral-to-worse). Single new variable: non-temporal stores for the
// 160 MB output in k_out (see k_out comment).
//
// K1: fused row-prefix + column chunk sums. One block per (chunk, b):
// 4 waves x 8 rows each. A wave scans a full 1024-px row: 4 float4 groups,
// local prefix-of-4, 6-round __shfl_up lane scan, carry between groups —
// no __syncthreads in the row loop. Centered values (x-0.5, x^2-1/3) keep
// SAT magnitude ~1e3 (verified absmax 3.9e-3 across all rounds).
// Each wave also accumulates per-column sums of its 8 rows in registers;
// one LDS round-trip at the end reduces the 4 waves into part[b][ch][x].
// ---------------------------------------------------------------------------
__global__ __launch_bounds__(256) void k_rowpart(const float* __restrict__ x,
                                                 float* __restrict__ P1,
                                                 float* __restrict__ P2,
                                                 float* __restrict__ part1,
                                                 float* __restrict__ part2) {
  const int ch = blockIdx.x, b = blockIdx.y;
  const int wave = threadIdx.x >> 6, lane = threadIdx.x & 63;
  const int row0 = ch * CHROWS_ + wave * (CHROWS_ / 4);  // 8 rows per wave

  float4 acc1[4], acc2[4];
  #pragma unroll
  for (int c = 0; c < 4; ++c) {
    acc1[c] = make_float4(0.f, 0.f, 0.f, 0.f);
    acc2[c] = make_float4(0.f, 0.f, 0.f, 0.f);
  }

  for (int rr = 0; rr < CHROWS_ / 4; ++rr) {
    const int y = row0 + rr;
    const size_t rowoff = ((size_t)b * H_ + y) * W_;
    float carry1 = 0.f, carry2 = 0.f;
    #pragma unroll
    for (int c = 0; c < 4; ++c) {
      const float4 v = reinterpret_cast<const float4*>(x + rowoff + c * 256)[lane];
      float l1[4], l2[4];
      l1[0] = v.x - 0.5f;
      l1[1] = l1[0] + (v.y - 0.5f);
      l1[2] = l1[1] + (v.z - 0.5f);
      l1[3] = l1[2] + (v.w - 0.5f);
      l2[0] = v.x * v.x - (1.0f / 3.0f);
      l2[1] = l2[0] + (v.y * v.y - (1.0f / 3.0f));
      l2[2] = l2[1] + (v.z * v.z - (1.0f / 3.0f));
      l2[3] = l2[2] + (v.w * v.w - (1.0f / 3.0f));
      const float s1 = l1[3], s2 = l2[3];
      float inc1 = s1, inc2 = s2;
      #pragma unroll
      for (int off = 1; off < 64; off <<= 1) {
        const float t1 = __shfl_up(inc1, off);
        const float t2 = __shfl_up(inc2, off);
        if (lane >= off) { inc1 += t1; inc2 += t2; }
      }
      const float base1 = carry1 + inc1 - s1;
      const float base2 = carry2 + inc2 - s2;
      float4 o1, o2;
      o1.x = base1 + l1[0]; o1.y = base1 + l1[1]; o1.z = base1 + l1[2]; o1.w = base1 + l1[3];
      o2.x = base2 + l2[0]; o2.y = base2 + l2[1]; o2.z = base2 + l2[2]; o2.w = base2 + l2[3];
      reinterpret_cast<float4*>(P1 + rowoff + c * 256)[lane] = o1;
      reinterpret_cast<float4*>(P2 + rowoff + c * 256)[lane] = o2;
      acc1[c].x += o1.x; acc1[c].y += o1.y; acc1[c].z += o1.z; acc1[c].w += o1.w;
      acc2[c].x += o2.x; acc2[c].y += o2.y; acc2[c].z += o2.z; acc2[c].w += o2.w;
      carry1 += __shfl(inc1, 63);
      carry2 += __shfl(inc2, 63);
    }
  }

  // cross-wave reduction of column sums -> part[b][ch][:]
  __shared__ float red[4][2][W_];  // 32 KB
  #pragma unroll
  for (int c = 0; c < 4; ++c) {
    reinterpret_cast<float4*>(&red[wave][0][c * 256])[lane] = acc1[c];
    reinterpret_cast<float4*>(&red[wave][1][c * 256])[lane] = acc2[c];
  }
  __syncthreads();
  const int t = threadIdx.x;  // thread t reduces cols 4t..4t+3
  float4 r1 = make_float4(0.f, 0.f, 0.f, 0.f), r2 = r1;
  #pragma unroll
  for (int w = 0; w < 4; ++w) {
    const float4 a = reinterpret_cast<const float4*>(&red[w][0][0])[t];
    const float4 c2 = reinterpret_cast<const float4*>(&red[w][1][0])[t];
    r1.x += a.x; r1.y += a.y; r1.z += a.z; r1.w += a.w;
    r2.x += c2.x; r2.y += c2.y; r2.z += c2.z; r2.w += c2.w;
  }
  const size_t po = ((size_t)(b * CHUNKS_ + ch)) * W_;
  reinterpret_cast<float4*>(part1 + po)[t] = r1;
  reinterpret_cast<float4*>(part2 + po)[t] = r2;
}

// ---------------------------------------------------------------------------
// K2: column rescan, absorbing the chunk-offset scan. Each block (b, ch,
// 256-col strip) sums the (<32, L2-resident) part rows below it for its
// exclusive offset, then rescans its 32 rows in place -> full 2-D SAT.
// 1024 blocks and a 32-long serial chain. (Round-0 verbatim.)
// ---------------------------------------------------------------------------
__global__ __launch_bounds__(256) void k_colscan(float* __restrict__ P1,
                                                 float* __restrict__ P2,
                                                 const float* __restrict__ part1,
                                                 const float* __restrict__ part2) {
  const int xx = blockIdx.x * 256 + threadIdx.x;
  const int ch = blockIdx.y, b = blockIdx.z;
  float r1 = 0.f, r2 = 0.f;
  for (int c = 0; c < ch; ++c) {   // block-uniform trip count
    const size_t o = ((size_t)(b * CHUNKS_ + c)) * W_ + xx;
    r1 += part1[o];
    r2 += part2[o];
  }
  float* p1 = P1 + ((size_t)b * H_ + (size_t)ch * CHROWS_) * W_ + xx;
  float* p2 = P2 + ((size_t)b * H_ + (size_t)ch * CHROWS_) * W_ + xx;
  #pragma unroll 8
  for (int i = 0; i < CHROWS_; ++i) {
    const size_t o = (size_t)i * W_;
    r1 += p1[o]; p1[o] = r1;
    r2 += p2[o]; p2[o] = r2;
  }
}

// ---------------------------------------------------------------------------
// K3: per-row vertical-difference strips in LDS (round-0 verbatim, proven
// ~65 us) with ONE change: the 160 MB output is written with
// __builtin_nontemporal_store (MUBUF nt). The output is streaming and
// never re-read; normal stores allocate its lines into L2/LLC and evict
// the ~640 MB of logical SAT-row re-reads this kernel depends on. NT
// stores preserve the cache for the SAT window. Single-variable test vs
// the 249.0 us round-0 measurement.
// ---------------------------------------------------------------------------
__global__ __launch_bounds__(256) void k_out(const float* __restrict__ S1,
                                             const float* __restrict__ S2,
                                             const float* __restrict__ kk,
                                             const float* __restrict__ RR,
                                             float* __restrict__ out) {
  const int i = blockIdx.x;
  const int xcd = i & 7;
  const int s = i >> 3;
  const int b = s >> 7;
  const int y = xcd * 128 + (s & 127);
  const int t = threadIdx.x;

  __shared__ float lds[2 * NW_ * W_];  // 40 KB

  const float* base1 = S1 + (size_t)b * H_ * W_;
  const float* base2 = S2 + (size_t)b * H_ * W_;
  const int rad[NW_] = {3, 7, 15, 31, 63};

  #pragma unroll
  for (int w = 0; w < NW_; ++w) {
    const int r = rad[w];
    const int yB = min(y + r, H_ - 1);
    const int yT = y - r - 1;
    const float4 fb1 = reinterpret_cast<const float4*>(base1 + (size_t)yB * W_)[t];
    const float4 fb2 = reinterpret_cast<const float4*>(base2 + (size_t)yB * W_)[t];
    float4 ft1 = {0.f, 0.f, 0.f, 0.f}, ft2 = {0.f, 0.f, 0.f, 0.f};
    if (yT >= 0) {   // block-uniform branch
      ft1 = reinterpret_cast<const float4*>(base1 + (size_t)yT * W_)[t];
      ft2 = reinterpret_cast<const float4*>(base2 + (size_t)yT * W_)[t];
    }
    float4 d1, d2;
    d1.x = fb1.x - ft1.x; d1.y = fb1.y - ft1.y; d1.z = fb1.z - ft1.z; d1.w = fb1.w - ft1.w;
    d2.x = fb2.x - ft2.x; d2.y = fb2.y - ft2.y; d2.z = fb2.z - ft2.z; d2.w = fb2.w - ft2.w;
    reinterpret_cast<float4*>(lds + (size_t)(2 * w) * W_)[t] = d1;
    reinterpret_cast<float4*>(lds + (size_t)(2 * w + 1) * W_)[t] = d2;
  }
  __syncthreads();

  #pragma unroll
  for (int w = 0; w < NW_; ++w) {
    const int r = rad[w];
    const float kw = kk[w];
    const float invR = __builtin_amdgcn_rcpf(RR[w]);
    const int yB = min(y + r, H_ - 1);
    const float rows = (float)(yB - max(y - r, 0) + 1);
    const float* D1 = lds + (size_t)(2 * w) * W_;
    const float* D2 = lds + (size_t)(2 * w + 1) * W_;
    float* orow = out + (((size_t)(b * NW_ + w)) * H_ + y) * W_;
    #pragma unroll
    for (int kp = 0; kp < 4; ++kp) {
      const int xx = t + kp * 256;
      const int xR = min(xx + r, W_ - 1);
      const int xL = xx - r - 1;
      float s1 = D1[xR];
      float s2 = D2[xR];
      if (xL >= 0) { s1 -= D1[xL]; s2 -= D2[xL]; }
      const float cols = (float)(xR - max(xx - r, 0) + 1);
      const float inv = __builtin_amdgcn_rcpf(rows * cols);
      const float Ex  = s1 * inv + 0.5f;
      const float Ex2 = s2 * inv + (1.0f / 3.0f);
      const float var = Ex2 - Ex * Ex;
      const float dev = __builtin_amdgcn_sqrtf(fmaxf(var, 1e-6f));
      __builtin_nontemporal_store(Ex * (1.0f + kw * (dev * invR - 1.0f)), &orow[xx]);
    }
  }
}

// ---------------------------------------------------------------------------
extern "C" void kernel_launch(void* const* d_in, const int* in_sizes, int n_in,
                              void* d_out, int out_size, void* d_ws, size_t ws_size,
                              hipStream_t stream) {
  const float* x  = (const float*)d_in[0];
  const float* kk = (const float*)d_in[1];
  const float* RR = (const float*)d_in[2];
  float* out = (float*)d_out;

  const size_t plane = (size_t)B_ * H_ * W_;            // 32 MB per moment
  float* P1 = (float*)d_ws;
  float* P2 = P1 + plane;
  float* part1 = P2 + plane;                            // 1 MB each
  float* part2 = part1 + (size_t)B_ * CHUNKS_ * W_;

  k_rowpart <<<dim3(CHUNKS_, B_),          256, 0, stream>>>(x, P1, P2, part1, part2);
  k_colscan <<<dim3(W_/256, CHUNKS_, B_),  256, 0, stream>>>(P1, P2, part1, part2);
  k_out     <<<dim3(B_ * H_),              256, 0, stream>>>(P1, P2, kk, RR, out);
}

// Round 8
// 242.875 us; speedup vs baseline: 1.1405x; 1.0057x over previous
//
#include <hip/hip_runtime.h>
#include <cstddef>

#define B_ 8
#define H_ 1024
#define W_ 1024
#define NW_ 5
#define CHUNKS_ 32
#define CHROWS_ (H_ / CHUNKS_)   // 32

// ---------------------------------------------------------------------------
// ROUND-8: R7 base (best-known, 244.2 us) with ONE change: k_out split into
// two window-passes over a reused 24 KB LDS buffer (was 40 KB) ->
// occupancy 4 -> 6 blocks/CU (16 -> 24 waves/CU). Pure occupancy/latency
// experiment; traffic, math, and stores identical.
//
// K1: fused row-prefix + column chunk sums (round-0 verbatim).
// ---------------------------------------------------------------------------
__global__ __launch_bounds__(256) void k_rowpart(const float* __restrict__ x,
                                                 float* __restrict__ P1,
                                                 float* __restrict__ P2,
                                                 float* __restrict__ part1,
                                                 float* __restrict__ part2) {
  const int ch = blockIdx.x, b = blockIdx.y;
  const int wave = threadIdx.x >> 6, lane = threadIdx.x & 63;
  const int row0 = ch * CHROWS_ + wave * (CHROWS_ / 4);  // 8 rows per wave

  float4 acc1[4], acc2[4];
  #pragma unroll
  for (int c = 0; c < 4; ++c) {
    acc1[c] = make_float4(0.f, 0.f, 0.f, 0.f);
    acc2[c] = make_float4(0.f, 0.f, 0.f, 0.f);
  }

  for (int rr = 0; rr < CHROWS_ / 4; ++rr) {
    const int y = row0 + rr;
    const size_t rowoff = ((size_t)b * H_ + y) * W_;
    float carry1 = 0.f, carry2 = 0.f;
    #pragma unroll
    for (int c = 0; c < 4; ++c) {
      const float4 v = reinterpret_cast<const float4*>(x + rowoff + c * 256)[lane];
      float l1[4], l2[4];
      l1[0] = v.x - 0.5f;
      l1[1] = l1[0] + (v.y - 0.5f);
      l1[2] = l1[1] + (v.z - 0.5f);
      l1[3] = l1[2] + (v.w - 0.5f);
      l2[0] = v.x * v.x - (1.0f / 3.0f);
      l2[1] = l2[0] + (v.y * v.y - (1.0f / 3.0f));
      l2[2] = l2[1] + (v.z * v.z - (1.0f / 3.0f));
      l2[3] = l2[2] + (v.w * v.w - (1.0f / 3.0f));
      const float s1 = l1[3], s2 = l2[3];
      float inc1 = s1, inc2 = s2;
      #pragma unroll
      for (int off = 1; off < 64; off <<= 1) {
        const float t1 = __shfl_up(inc1, off);
        const float t2 = __shfl_up(inc2, off);
        if (lane >= off) { inc1 += t1; inc2 += t2; }
      }
      const float base1 = carry1 + inc1 - s1;
      const float base2 = carry2 + inc2 - s2;
      float4 o1, o2;
      o1.x = base1 + l1[0]; o1.y = base1 + l1[1]; o1.z = base1 + l1[2]; o1.w = base1 + l1[3];
      o2.x = base2 + l2[0]; o2.y = base2 + l2[1]; o2.z = base2 + l2[2]; o2.w = base2 + l2[3];
      reinterpret_cast<float4*>(P1 + rowoff + c * 256)[lane] = o1;
      reinterpret_cast<float4*>(P2 + rowoff + c * 256)[lane] = o2;
      acc1[c].x += o1.x; acc1[c].y += o1.y; acc1[c].z += o1.z; acc1[c].w += o1.w;
      acc2[c].x += o2.x; acc2[c].y += o2.y; acc2[c].z += o2.z; acc2[c].w += o2.w;
      carry1 += __shfl(inc1, 63);
      carry2 += __shfl(inc2, 63);
    }
  }

  // cross-wave reduction of column sums -> part[b][ch][:]
  __shared__ float red[4][2][W_];  // 32 KB
  #pragma unroll
  for (int c = 0; c < 4; ++c) {
    reinterpret_cast<float4*>(&red[wave][0][c * 256])[lane] = acc1[c];
    reinterpret_cast<float4*>(&red[wave][1][c * 256])[lane] = acc2[c];
  }
  __syncthreads();
  const int t = threadIdx.x;  // thread t reduces cols 4t..4t+3
  float4 r1 = make_float4(0.f, 0.f, 0.f, 0.f), r2 = r1;
  #pragma unroll
  for (int w = 0; w < 4; ++w) {
    const float4 a = reinterpret_cast<const float4*>(&red[w][0][0])[t];
    const float4 c2 = reinterpret_cast<const float4*>(&red[w][1][0])[t];
    r1.x += a.x; r1.y += a.y; r1.z += a.z; r1.w += a.w;
    r2.x += c2.x; r2.y += c2.y; r2.z += c2.z; r2.w += c2.w;
  }
  const size_t po = ((size_t)(b * CHUNKS_ + ch)) * W_;
  reinterpret_cast<float4*>(part1 + po)[t] = r1;
  reinterpret_cast<float4*>(part2 + po)[t] = r2;
}

// ---------------------------------------------------------------------------
// K2: column rescan, absorbing the chunk-offset scan (round-0 verbatim).
// ---------------------------------------------------------------------------
__global__ __launch_bounds__(256) void k_colscan(float* __restrict__ P1,
                                                 float* __restrict__ P2,
                                                 const float* __restrict__ part1,
                                                 const float* __restrict__ part2) {
  const int xx = blockIdx.x * 256 + threadIdx.x;
  const int ch = blockIdx.y, b = blockIdx.z;
  float r1 = 0.f, r2 = 0.f;
  for (int c = 0; c < ch; ++c) {   // block-uniform trip count
    const size_t o = ((size_t)(b * CHUNKS_ + c)) * W_ + xx;
    r1 += part1[o];
    r2 += part2[o];
  }
  float* p1 = P1 + ((size_t)b * H_ + (size_t)ch * CHROWS_) * W_ + xx;
  float* p2 = P2 + ((size_t)b * H_ + (size_t)ch * CHROWS_) * W_ + xx;
  #pragma unroll 8
  for (int i = 0; i < CHROWS_; ++i) {
    const size_t o = (size_t)i * W_;
    r1 += p1[o]; p1[o] = r1;
    r2 += p2[o]; p2[o] = r2;
  }
}

// ---------------------------------------------------------------------------
// K3: per-row vertical-difference strips in LDS, NT output stores (R7),
// now TWO window-passes over a reused 24 KB buffer:
//   pass A: windows 0..2 -> 6 strips (24 KB); compute+store.
//   pass B: windows 3..4 -> 4 strips (16 KB, reusing same LDS); compute+store.
// LDS 40 KB -> 24 KB lifts occupancy 4 -> 6 blocks/CU for latency hiding
// of the gathered row-loads. 3 barriers instead of 1. Same loads, same
// arithmetic, same NT stores -> bit-identical output.
// ---------------------------------------------------------------------------
__global__ __launch_bounds__(256) void k_out(const float* __restrict__ S1,
                                             const float* __restrict__ S2,
                                             const float* __restrict__ kk,
                                             const float* __restrict__ RR,
                                             float* __restrict__ out) {
  const int i = blockIdx.x;
  const int xcd = i & 7;
  const int s = i >> 3;
  const int b = s >> 7;
  const int y = xcd * 128 + (s & 127);
  const int t = threadIdx.x;

  __shared__ float lds[6 * W_];  // 24 KB, reused across the two passes

  const float* base1 = S1 + (size_t)b * H_ * W_;
  const float* base2 = S2 + (size_t)b * H_ * W_;
  const int rad[NW_] = {3, 7, 15, 31, 63};

  // ---------------- pass A: windows 0,1,2 ----------------
  #pragma unroll
  for (int wi = 0; wi < 3; ++wi) {
    const int r = rad[wi];
    const int yB = min(y + r, H_ - 1);
    const int yT = y - r - 1;
    const float4 fb1 = reinterpret_cast<const float4*>(base1 + (size_t)yB * W_)[t];
    const float4 fb2 = reinterpret_cast<const float4*>(base2 + (size_t)yB * W_)[t];
    float4 ft1 = {0.f, 0.f, 0.f, 0.f}, ft2 = {0.f, 0.f, 0.f, 0.f};
    if (yT >= 0) {   // block-uniform branch
      ft1 = reinterpret_cast<const float4*>(base1 + (size_t)yT * W_)[t];
      ft2 = reinterpret_cast<const float4*>(base2 + (size_t)yT * W_)[t];
    }
    float4 d1, d2;
    d1.x = fb1.x - ft1.x; d1.y = fb1.y - ft1.y; d1.z = fb1.z - ft1.z; d1.w = fb1.w - ft1.w;
    d2.x = fb2.x - ft2.x; d2.y = fb2.y - ft2.y; d2.z = fb2.z - ft2.z; d2.w = fb2.w - ft2.w;
    reinterpret_cast<float4*>(lds + (size_t)(2 * wi) * W_)[t] = d1;
    reinterpret_cast<float4*>(lds + (size_t)(2 * wi + 1) * W_)[t] = d2;
  }
  __syncthreads();

  #pragma unroll
  for (int wi = 0; wi < 3; ++wi) {
    const int r = rad[wi];
    const float kw = kk[wi];
    const float invR = __builtin_amdgcn_rcpf(RR[wi]);
    const int yB = min(y + r, H_ - 1);
    const float rows = (float)(yB - max(y - r, 0) + 1);
    const float* D1 = lds + (size_t)(2 * wi) * W_;
    const float* D2 = lds + (size_t)(2 * wi + 1) * W_;
    float* orow = out + (((size_t)(b * NW_ + wi)) * H_ + y) * W_;
    #pragma unroll
    for (int kp = 0; kp < 4; ++kp) {
      const int xx = t + kp * 256;
      const int xR = min(xx + r, W_ - 1);
      const int xL = xx - r - 1;
      float s1 = D1[xR];
      float s2 = D2[xR];
      if (xL >= 0) { s1 -= D1[xL]; s2 -= D2[xL]; }
      const float cols = (float)(xR - max(xx - r, 0) + 1);
      const float inv = __builtin_amdgcn_rcpf(rows * cols);
      const float Ex  = s1 * inv + 0.5f;
      const float Ex2 = s2 * inv + (1.0f / 3.0f);
      const float var = Ex2 - Ex * Ex;
      const float dev = __builtin_amdgcn_sqrtf(fmaxf(var, 1e-6f));
      __builtin_nontemporal_store(Ex * (1.0f + kw * (dev * invR - 1.0f)), &orow[xx]);
    }
  }
  __syncthreads();   // all pass-A reads done before pass-B overwrites LDS

  // ---------------- pass B: windows 3,4 ----------------
  #pragma unroll
  for (int wi = 0; wi < 2; ++wi) {
    const int r = rad[3 + wi];
    const int yB = min(y + r, H_ - 1);
    const int yT = y - r - 1;
    const float4 fb1 = reinterpret_cast<const float4*>(base1 + (size_t)yB * W_)[t];
    const float4 fb2 = reinterpret_cast<const float4*>(base2 + (size_t)yB * W_)[t];
    float4 ft1 = {0.f, 0.f, 0.f, 0.f}, ft2 = {0.f, 0.f, 0.f, 0.f};
    if (yT >= 0) {   // block-uniform branch
      ft1 = reinterpret_cast<const float4*>(base1 + (size_t)yT * W_)[t];
      ft2 = reinterpret_cast<const float4*>(base2 + (size_t)yT * W_)[t];
    }
    float4 d1, d2;
    d1.x = fb1.x - ft1.x; d1.y = fb1.y - ft1.y; d1.z = fb1.z - ft1.z; d1.w = fb1.w - ft1.w;
    d2.x = fb2.x - ft2.x; d2.y = fb2.y - ft2.y; d2.z = fb2.z - ft2.z; d2.w = fb2.w - ft2.w;
    reinterpret_cast<float4*>(lds + (size_t)(2 * wi) * W_)[t] = d1;
    reinterpret_cast<float4*>(lds + (size_t)(2 * wi + 1) * W_)[t] = d2;
  }
  __syncthreads();

  #pragma unroll
  for (int wi = 0; wi < 2; ++wi) {
    const int w = 3 + wi;
    const int r = rad[w];
    const float kw = kk[w];
    const float invR = __builtin_amdgcn_rcpf(RR[w]);
    const int yB = min(y + r, H_ - 1);
    const float rows = (float)(yB - max(y - r, 0) + 1);
    const float* D1 = lds + (size_t)(2 * wi) * W_;
    const float* D2 = lds + (size_t)(2 * wi + 1) * W_;
    float* orow = out + (((size_t)(b * NW_ + w)) * H_ + y) * W_;
    #pragma unroll
    for (int kp = 0; kp < 4; ++kp) {
      const int xx = t + kp * 256;
      const int xR = min(xx + r, W_ - 1);
      const int xL = xx - r - 1;
      float s1 = D1[xR];
      float s2 = D2[xR];
      if (xL >= 0) { s1 -= D1[xL]; s2 -= D2[xL]; }
      const float cols = (float)(xR - max(xx - r, 0) + 1);
      const float inv = __builtin_amdgcn_rcpf(rows * cols);
      const float Ex  = s1 * inv + 0.5f;
      const float Ex2 = s2 * inv + (1.0f / 3.0f);
      const float var = Ex2 - Ex * Ex;
      const float dev = __builtin_amdgcn_sqrtf(fmaxf(var, 1e-6f));
      __builtin_nontemporal_store(Ex * (1.0f + kw * (dev * invR - 1.0f)), &orow[xx]);
    }
  }
}

// ---------------------------------------------------------------------------
extern "C" void kernel_launch(void* const* d_in, const int* in_sizes, int n_in,
                              void* d_out, int out_size, void* d_ws, size_t ws_size,
                              hipStream_t stream) {
  const float* x  = (const float*)d_in[0];
  const float* kk = (const float*)d_in[1];
  const float* RR = (const float*)d_in[2];
  float* out = (float*)d_out;

  const size_t plane = (size_t)B_ * H_ * W_;            // 32 MB per moment
  float* P1 = (float*)d_ws;
  float* P2 = P1 + plane;
  float* part1 = P2 + plane;                            // 1 MB each
  float* part2 = part1 + (size_t)B_ * CHUNKS_ * W_;

  k_rowpart <<<dim3(CHUNKS_, B_),          256, 0, stream>>>(x, P1, P2, part1, part2);
  k_colscan <<<dim3(W_/256, CHUNKS_, B_),  256, 0, stream>>>(P1, P2, part1, part2);
  k_out     <<<dim3(B_ * H_),              256, 0, stream>>>(P1, P2, kk, RR, out);
}